// Round 1
// baseline (70.705 us; speedup 1.0000x reference)
//
#include <hip/hip_runtime.h>
#include <math.h>

#define THREADS 256
#define P 4          // pred points per thread
#define MCHUNK 1024  // target points staged in LDS per block

// Fill the per-point min arrays with +inf (bit pattern 0x7F800000).
__global__ void init_min_ws(int* __restrict__ ws, int n) {
    int i = blockIdx.x * blockDim.x + threadIdx.x;
    if (i < n) ws[i] = 0x7F800000;
}

// One launch covers BOTH chamfer directions (blockIdx.z selects).
// For each "x" point, min over a chunk of "y" points of
//   d2 = x2 + y2 - 2*dot(x,y); we track min(y2 - 2*dot) and add x2 at the end.
// Result is atomicMin'd (int-punned; values >= ~0) into outmin[b*N + n].
__global__ __launch_bounds__(THREADS) void chamfer_kernel(
    const float* __restrict__ pred, const float* __restrict__ targ,
    int* __restrict__ min_pred, int* __restrict__ min_targ,
    int N, int M, int chunksPerBatch)
{
    const float* xsrc;
    const float* ysrc;
    int* outmin;
    if (blockIdx.z == 0) { xsrc = pred; ysrc = targ; outmin = min_pred; }
    else                 { xsrc = targ; ysrc = pred; outmin = min_targ; }

    __shared__ float4 sy[MCHUNK];

    const int b   = blockIdx.x / chunksPerBatch;
    const int n0  = (blockIdx.x % chunksPerBatch) * (THREADS * P);
    const int m0  = blockIdx.y * MCHUNK;
    const int tid = threadIdx.x;

    // Stage target chunk into LDS as (x, y, z, |y|^2).
    for (int j = tid; j < MCHUNK; j += THREADS) {
        const float* yp = ysrc + (size_t)(b * M + m0 + j) * 3;
        float yx = yp[0], yy = yp[1], yz = yp[2];
        sy[j] = make_float4(yx, yy, yz, fmaf(yx, yx, fmaf(yy, yy, yz * yz)));
    }
    __syncthreads();

    float px[P], py[P], pz[P], mn[P];
#pragma unroll
    for (int p = 0; p < P; ++p) {
        int n = n0 + tid + p * THREADS;
        const float* xp = xsrc + (size_t)(b * N + n) * 3;
        px[p] = xp[0];
        py[p] = xp[1];
        pz[p] = xp[2];
        mn[p] = INFINITY;
    }

#pragma unroll 4
    for (int j = 0; j < MCHUNK; ++j) {
        float4 t = sy[j];  // broadcast read: all lanes same address
#pragma unroll
        for (int p = 0; p < P; ++p) {
            float dot = fmaf(pz[p], t.z, fmaf(py[p], t.y, px[p] * t.x));
            float v   = fmaf(dot, -2.0f, t.w);  // y2 - 2*dot
            mn[p] = fminf(mn[p], v);
        }
    }

#pragma unroll
    for (int p = 0; p < P; ++p) {
        int n = n0 + tid + p * THREADS;
        float x2 = fmaf(px[p], px[p], fmaf(py[p], py[p], pz[p] * pz[p]));
        float d  = mn[p] + x2;  // >= 0 up to rounding noise
        atomicMin(&outmin[b * N + n], __float_as_int(d));
    }
}

// Single-block final reduction: dist = mean(minx) + mean(miny); outputs
// (loss, dist, rate).
__global__ __launch_bounds__(1024) void reduce_final(
    const int* __restrict__ min_x, const int* __restrict__ min_y,
    const float* __restrict__ fbpp, float* __restrict__ out, int total)
{
    __shared__ float s_x[16];
    __shared__ float s_y[16];
    const int tid = threadIdx.x;

    float sx = 0.0f, syv = 0.0f;
    for (int i = tid; i < total; i += 1024) {
        sx  += __int_as_float(min_x[i]);
        syv += __int_as_float(min_y[i]);
    }
    for (int off = 32; off > 0; off >>= 1) {
        sx  += __shfl_down(sx, off);
        syv += __shfl_down(syv, off);
    }
    const int wave = tid >> 6;
    if ((tid & 63) == 0) { s_x[wave] = sx; s_y[wave] = syv; }
    __syncthreads();
    if (tid == 0) {
        float tx = 0.0f, ty = 0.0f;
#pragma unroll
        for (int w = 0; w < 16; ++w) { tx += s_x[w]; ty += s_y[w]; }
        float dist = tx / (float)total + ty / (float)total;
        float rate = fbpp[0];
        out[0] = dist + rate;
        out[1] = dist;
        out[2] = rate;
    }
}

extern "C" void kernel_launch(void* const* d_in, const int* in_sizes, int n_in,
                              void* d_out, int out_size, void* d_ws, size_t ws_size,
                              hipStream_t stream) {
    const float* pred = (const float*)d_in[0];
    const float* targ = (const float*)d_in[1];
    const float* fbpp = (const float*)d_in[2];
    float* out = (float*)d_out;

    const int B = 4;
    const int totalPts = in_sizes[0] / 3;  // B*N
    const int N = totalPts / B;            // 8192
    const int M = N;                       // symmetric problem

    int* minx = (int*)d_ws;                // B*N ints
    int* miny = minx + totalPts;           // B*M ints

    const int wsElems = 2 * totalPts;
    init_min_ws<<<(wsElems + 255) / 256, 256, 0, stream>>>(minx, wsElems);

    const int chunksPerBatch = N / (THREADS * P);        // 8
    dim3 grid(B * chunksPerBatch, M / MCHUNK, 2);        // (32, 8, 2)
    chamfer_kernel<<<grid, THREADS, 0, stream>>>(pred, targ, minx, miny,
                                                 N, M, chunksPerBatch);

    reduce_final<<<1, 1024, 0, stream>>>(minx, miny, fbpp, out, totalPts);
}

// Round 2
// 59.413 us; speedup vs baseline: 1.1901x; 1.1901x over previous
//
#include <hip/hip_runtime.h>
#include <math.h>

#define THREADS 256
#define P 8          // pred points per thread
#define MCHUNK 256   // target points staged in LDS per block

// Fill the per-point min arrays with +inf (bit pattern 0x7F800000).
__global__ void init_min_ws(int* __restrict__ ws, int n) {
    int i = blockIdx.x * blockDim.x + threadIdx.x;
    if (i < n) ws[i] = 0x7F800000;
}

// One launch covers BOTH chamfer directions (blockIdx.z selects).
// LDS holds (-2*y.x, -2*y.y, -2*y.z, |y|^2); per pair:
//   v = fma(px,ax, fma(py,ay, fma(pz,az, y2)))  == y2 - 2*dot   (3 fma)
// running min over two j's at once -> v_min3_f32 fusion (0.5 op/pair).
// Final d = min_v + |x|^2, atomicMin (int-punned, non-negative) per point.
__global__ __launch_bounds__(THREADS) void chamfer_kernel(
    const float* __restrict__ pred, const float* __restrict__ targ,
    int* __restrict__ min_pred, int* __restrict__ min_targ,
    int N, int M, int chunksPerBatch)
{
    const float* xsrc;
    const float* ysrc;
    int* outmin;
    if (blockIdx.z == 0) { xsrc = pred; ysrc = targ; outmin = min_pred; }
    else                 { xsrc = targ; ysrc = pred; outmin = min_targ; }

    __shared__ float4 sy[MCHUNK];

    const int b   = blockIdx.x / chunksPerBatch;
    const int n0  = (blockIdx.x % chunksPerBatch) * (THREADS * P);
    const int m0  = blockIdx.y * MCHUNK;
    const int tid = threadIdx.x;

    // Stage target chunk into LDS as (-2x, -2y, -2z, |y|^2).
    for (int j = tid; j < MCHUNK; j += THREADS) {
        const float* yp = ysrc + (size_t)(b * M + m0 + j) * 3;
        float yx = yp[0], yy = yp[1], yz = yp[2];
        sy[j] = make_float4(-2.0f * yx, -2.0f * yy, -2.0f * yz,
                            fmaf(yx, yx, fmaf(yy, yy, yz * yz)));
    }
    __syncthreads();

    float px[P], py[P], pz[P], mn[P];
#pragma unroll
    for (int p = 0; p < P; ++p) {
        int n = n0 + tid + p * THREADS;
        const float* xp = xsrc + (size_t)(b * N + n) * 3;
        px[p] = xp[0];
        py[p] = xp[1];
        pz[p] = xp[2];
        mn[p] = INFINITY;
    }

#pragma unroll 2
    for (int j = 0; j < MCHUNK; j += 2) {
        float4 a = sy[j];      // broadcast reads: all lanes same address
        float4 c = sy[j + 1];
#pragma unroll
        for (int p = 0; p < P; ++p) {
            float va = fmaf(px[p], a.x, fmaf(py[p], a.y, fmaf(pz[p], a.z, a.w)));
            float vc = fmaf(px[p], c.x, fmaf(py[p], c.y, fmaf(pz[p], c.z, c.w)));
            mn[p] = fminf(fminf(mn[p], va), vc);  // -> v_min3_f32
        }
    }

#pragma unroll
    for (int p = 0; p < P; ++p) {
        int n = n0 + tid + p * THREADS;
        float x2 = fmaf(px[p], px[p], fmaf(py[p], py[p], pz[p] * pz[p]));
        float d  = mn[p] + x2;  // >= 0 up to rounding noise
        atomicMin(&outmin[b * N + n], __float_as_int(d));
    }
}

// Single-block final reduction: dist = mean(minx) + mean(miny); outputs
// (loss, dist, rate).
__global__ __launch_bounds__(1024) void reduce_final(
    const int* __restrict__ min_x, const int* __restrict__ min_y,
    const float* __restrict__ fbpp, float* __restrict__ out, int total)
{
    __shared__ float s_x[16];
    __shared__ float s_y[16];
    const int tid = threadIdx.x;

    float sx = 0.0f, syv = 0.0f;
    for (int i = tid; i < total; i += 1024) {
        sx  += __int_as_float(min_x[i]);
        syv += __int_as_float(min_y[i]);
    }
    for (int off = 32; off > 0; off >>= 1) {
        sx  += __shfl_down(sx, off);
        syv += __shfl_down(syv, off);
    }
    const int wave = tid >> 6;
    if ((tid & 63) == 0) { s_x[wave] = sx; s_y[wave] = syv; }
    __syncthreads();
    if (tid == 0) {
        float tx = 0.0f, ty = 0.0f;
#pragma unroll
        for (int w = 0; w < 16; ++w) { tx += s_x[w]; ty += s_y[w]; }
        float dist = tx / (float)total + ty / (float)total;
        float rate = fbpp[0];
        out[0] = dist + rate;
        out[1] = dist;
        out[2] = rate;
    }
}

extern "C" void kernel_launch(void* const* d_in, const int* in_sizes, int n_in,
                              void* d_out, int out_size, void* d_ws, size_t ws_size,
                              hipStream_t stream) {
    const float* pred = (const float*)d_in[0];
    const float* targ = (const float*)d_in[1];
    const float* fbpp = (const float*)d_in[2];
    float* out = (float*)d_out;

    const int B = 4;
    const int totalPts = in_sizes[0] / 3;  // B*N
    const int N = totalPts / B;            // 8192
    const int M = N;                       // symmetric problem

    int* minx = (int*)d_ws;                // B*N ints
    int* miny = minx + totalPts;           // B*M ints

    const int wsElems = 2 * totalPts;
    init_min_ws<<<(wsElems + 255) / 256, 256, 0, stream>>>(minx, wsElems);

    const int chunksPerBatch = N / (THREADS * P);        // 4
    dim3 grid(B * chunksPerBatch, M / MCHUNK, 2);        // (16, 32, 2)
    chamfer_kernel<<<grid, THREADS, 0, stream>>>(pred, targ, minx, miny,
                                                 N, M, chunksPerBatch);

    reduce_final<<<1, 1024, 0, stream>>>(minx, miny, fbpp, out, totalPts);
}

// Round 4
// 34.527 us; speedup vs baseline: 2.0478x; 1.7208x over previous
//
#include <hip/hip_runtime.h>
#include <math.h>

typedef _Float16 f16x8 __attribute__((ext_vector_type(8)));
typedef __fp16   fp16v2 __attribute__((ext_vector_type(2)));
typedef float    f32x16 __attribute__((ext_vector_type(16)));

#define THREADS 256
#define YCHUNK  512   // y points staged in LDS per chunk
#define XPB     128   // x points per block (4 waves * 32 cols)

static __device__ inline unsigned pk2(float a, float b) {
    fp16v2 h = __builtin_amdgcn_cvt_pkrtz(a, b);
    return __builtin_bit_cast(unsigned, h);
}

// One wave owns 32 x-points (MFMA cols) and scans ALL y (MFMA rows, 32/instr).
// A[y,k] = (y0,y1,y2,|y|^2) f16, B[k,x] = (-2x0,-2x1,-2x2,1) f16, K slots 4..15
// are zero IN B, so garbage in A's upper fragment contributes 0 regardless of
// which K-layout hypothesis (contiguous k=(l>>5)*8+i or split) the HW uses.
// acc = d^2 - |x|^2; fold per-pair mins on VALU, add |x|^2 (f32) at the end.
// Row/col lane permutations are harmless: min over rows, mean over cols.
__global__ __launch_bounds__(THREADS) void chamfer_kernel(
    const float* __restrict__ pred, const float* __restrict__ targ,
    float* __restrict__ partials, int N)
{
    const int dir = blockIdx.z;
    const float* xsrc = dir == 0 ? pred : targ;
    const float* ysrc = dir == 0 ? targ : pred;
    const int b = blockIdx.y;

    __shared__ uint2 sy[YCHUNK];   // (y0,y1) (y2,|y|^2) packed f16
    __shared__ float swave[4];

    const int tid  = threadIdx.x;
    const int lane = tid & 63;
    const int wave = tid >> 6;
    const int col  = lane & 31;

    // Load this lane's x column (lanes 32-63 duplicate lanes 0-31).
    const size_t xi = (size_t)(b * N + blockIdx.x * XPB + wave * 32 + col) * 3;
    const float x0 = xsrc[xi], x1 = xsrc[xi + 1], x2 = xsrc[xi + 2];

    const bool act = lane < 32;
    f16x8 bf;
    bf[0] = act ? (_Float16)(-2.0f * x0) : (_Float16)0.0f;
    bf[1] = act ? (_Float16)(-2.0f * x1) : (_Float16)0.0f;
    bf[2] = act ? (_Float16)(-2.0f * x2) : (_Float16)0.0f;
    bf[3] = act ? (_Float16)1.0f : (_Float16)0.0f;
    bf[4] = bf[5] = bf[6] = bf[7] = (_Float16)0.0f;

    f32x16 zacc;
    f32x16 vmin;
#pragma unroll
    for (int r = 0; r < 16; ++r) { zacc[r] = 0.0f; vmin[r] = INFINITY; }

    const float* ybase = ysrc + (size_t)b * N * 3;
    const int nchunks = N / YCHUNK;

    // Preload chunk 0 staging registers (2 y-points per thread).
    float a0c = ybase[(size_t)tid * 3 + 0];
    float a1c = ybase[(size_t)tid * 3 + 1];
    float a2c = ybase[(size_t)tid * 3 + 2];
    float b0c = ybase[(size_t)(tid + 256) * 3 + 0];
    float b1c = ybase[(size_t)(tid + 256) * 3 + 1];
    float b2c = ybase[(size_t)(tid + 256) * 3 + 2];

    for (int c = 0; c < nchunks; ++c) {
        __syncthreads();  // previous compute phase done reading sy
        float na = fmaf(a0c, a0c, fmaf(a1c, a1c, a2c * a2c));
        float nb = fmaf(b0c, b0c, fmaf(b1c, b1c, b2c * b2c));
        sy[tid]       = make_uint2(pk2(a0c, a1c), pk2(a2c, na));
        sy[tid + 256] = make_uint2(pk2(b0c, b1c), pk2(b2c, nb));
        // Prefetch next chunk into regs; HBM/L2 latency hides under MFMAs.
        if (c + 1 < nchunks) {
            size_t p = (size_t)((c + 1) * YCHUNK + tid) * 3;
            a0c = ybase[p];       a1c = ybase[p + 1];       a2c = ybase[p + 2];
            b0c = ybase[p + 768]; b1c = ybase[p + 769];     b2c = ybase[p + 770];
        }
        __syncthreads();

#pragma unroll
        for (int i = 0; i < YCHUNK / 32; i += 2) {
            uint2 lo0 = sy[i * 32 + col];
            uint2 lo1 = sy[(i + 1) * 32 + col];
            uint4 av0 = make_uint4(lo0.x, lo0.y, 0u, 0u);
            uint4 av1 = make_uint4(lo1.x, lo1.y, 0u, 0u);
            f32x16 acc0 = __builtin_amdgcn_mfma_f32_32x32x16_f16(
                __builtin_bit_cast(f16x8, av0), bf, zacc, 0, 0, 0);
            f32x16 acc1 = __builtin_amdgcn_mfma_f32_32x32x16_f16(
                __builtin_bit_cast(f16x8, av1), bf, zacc, 0, 0, 0);
#pragma unroll
            for (int r = 0; r < 16; ++r)
                vmin[r] = fminf(fminf(vmin[r], acc0[r]), acc1[r]);  // v_min3
        }
    }

    // Reduce 16 regs -> 1, then across the two row-halves (lane ^ 32).
    float v = vmin[0];
#pragma unroll
    for (int r = 1; r < 16; ++r) v = fminf(v, vmin[r]);
    v = fminf(v, __shfl_xor(v, 32));
    float d = v + fmaf(x0, x0, fmaf(x1, x1, x2 * x2));  // + |x|^2 in f32

    // Sum d over the 32 cols of this wave (both halves hold identical values).
#pragma unroll
    for (int off = 16; off > 0; off >>= 1) d += __shfl_xor(d, off);
    if (lane == 0) swave[wave] = d;
    __syncthreads();
    if (tid == 0) {
        float s = swave[0] + swave[1] + swave[2] + swave[3];
        int bid = blockIdx.x + gridDim.x * (blockIdx.y + gridDim.y * blockIdx.z);
        partials[bid] = s;
    }
}

// partials[0 .. nPerDir-1] = dir0 block sums, [nPerDir .. 2*nPerDir-1] = dir1.
__global__ __launch_bounds__(512) void finalize(
    const float* __restrict__ partials, const float* __restrict__ fbpp,
    float* __restrict__ out, int nPerDir, int totalPts)
{
    __shared__ float sw[8];
    const int tid = threadIdx.x;
    float v = (tid < 2 * nPerDir) ? partials[tid] : 0.0f;
#pragma unroll
    for (int off = 32; off > 0; off >>= 1) v += __shfl_xor(v, off);
    if ((tid & 63) == 0) sw[tid >> 6] = v;
    __syncthreads();
    if (tid == 0) {
        float s0 = sw[0] + sw[1] + sw[2] + sw[3];  // dir0 (waves 0-3)
        float s1 = sw[4] + sw[5] + sw[6] + sw[7];  // dir1 (waves 4-7)
        float inv = 1.0f / (float)totalPts;
        float dist = s0 * inv + s1 * inv;
        float rate = fbpp[0];
        out[0] = dist + rate;
        out[1] = dist;
        out[2] = rate;
    }
}

extern "C" void kernel_launch(void* const* d_in, const int* in_sizes, int n_in,
                              void* d_out, int out_size, void* d_ws, size_t ws_size,
                              hipStream_t stream) {
    const float* pred = (const float*)d_in[0];
    const float* targ = (const float*)d_in[1];
    const float* fbpp = (const float*)d_in[2];
    float* out = (float*)d_out;

    const int B = 4;
    const int N = in_sizes[0] / (B * 3);   // 8192
    float* partials = (float*)d_ws;        // 2 * B * (N/XPB) floats

    dim3 grid(N / XPB, B, 2);              // (64, 4, 2) = 512 blocks
    chamfer_kernel<<<grid, THREADS, 0, stream>>>(pred, targ, partials, N);

    const int nPerDir = (N / XPB) * B;     // 256
    finalize<<<1, 512, 0, stream>>>(partials, fbpp, out, nPerDir, B * N);
}

// Round 5
// 32.461 us; speedup vs baseline: 2.1782x; 1.0636x over previous
//
#include <hip/hip_runtime.h>
#include <math.h>

typedef _Float16 f16x8 __attribute__((ext_vector_type(8)));
typedef __fp16   fp16v2 __attribute__((ext_vector_type(2)));
typedef float    f32x16 __attribute__((ext_vector_type(16)));

#define THREADS 256
#define YCHUNK  4096  // y points per LDS mega-chunk (32 KB, static-LDS safe)
#define XPB     128   // x points per block (4 waves * 32 cols)

static __device__ inline unsigned pk2(float a, float b) {
    fp16v2 h = __builtin_amdgcn_cvt_pkrtz(a, b);
    return __builtin_bit_cast(unsigned, h);
}

// One wave owns 32 x-points (MFMA cols) and scans ALL y (MFMA rows, 32/instr).
// A[y,k] = (y0,y1,y2,|y|^2) f16; B[k,x] = (-2x0,-2x1,-2x2,1) f16 with all
// other K slots zero IN B, so any garbage in A's unused K slots contributes 0.
// acc = d^2 - |x|^2; running min on VALU (v_min3), add |x|^2 (f32) at the end.
// Only 2 mega-chunks -> 4 barriers total; main loop is barrier-free.
__global__ __launch_bounds__(THREADS) void chamfer_kernel(
    const float* __restrict__ pred, const float* __restrict__ targ,
    float* __restrict__ partials, int N)
{
    const int dir = blockIdx.z;
    const float* xsrc = dir == 0 ? pred : targ;
    const float* ysrc = dir == 0 ? targ : pred;
    const int b = blockIdx.y;

    __shared__ uint2 sy[YCHUNK];   // (y0,y1) (y2,|y|^2) packed f16
    __shared__ float swave[4];

    const int tid  = threadIdx.x;
    const int lane = tid & 63;
    const int wave = tid >> 6;
    const int col  = lane & 31;

    // This lane's x column (lanes 32-63 duplicate lanes 0-31).
    const size_t xi = (size_t)(b * N + blockIdx.x * XPB + wave * 32 + col) * 3;
    const float x0 = xsrc[xi], x1 = xsrc[xi + 1], x2 = xsrc[xi + 2];

    const bool act = lane < 32;
    f16x8 bf;
    bf[0] = act ? (_Float16)(-2.0f * x0) : (_Float16)0.0f;
    bf[1] = act ? (_Float16)(-2.0f * x1) : (_Float16)0.0f;
    bf[2] = act ? (_Float16)(-2.0f * x2) : (_Float16)0.0f;
    bf[3] = act ? (_Float16)1.0f : (_Float16)0.0f;
    bf[4] = bf[5] = bf[6] = bf[7] = (_Float16)0.0f;

    f32x16 zacc;
    f32x16 vmin;
#pragma unroll
    for (int r = 0; r < 16; ++r) { zacc[r] = 0.0f; vmin[r] = INFINITY; }

    const float* ybase = ysrc + (size_t)b * N * 3;
    const int nchunks = N / YCHUNK;   // 2

    for (int c = 0; c < nchunks; ++c) {
        __syncthreads();  // previous compute phase done reading sy
        // Stage 4096 y-points (16 per thread), coalesced 3-dword loads.
#pragma unroll
        for (int j = 0; j < YCHUNK / THREADS; ++j) {
            const int   yj = j * THREADS + tid;
            const float* yp = ybase + (size_t)(c * YCHUNK + yj) * 3;
            float y0 = yp[0], y1 = yp[1], y2v = yp[2];
            float nn = fmaf(y0, y0, fmaf(y1, y1, y2v * y2v));
            sy[yj] = make_uint2(pk2(y0, y1), pk2(y2v, nn));
        }
        __syncthreads();

        // Barrier-free main loop: ds_read_b64 -> MFMA -> v_min3 stream.
#pragma unroll 2
        for (int i = 0; i < YCHUNK / 32; i += 2) {
            uint2 lo0 = sy[i * 32 + col];
            uint2 lo1 = sy[(i + 1) * 32 + col];
            uint4 av0 = make_uint4(lo0.x, lo0.y, 0u, 0u);
            uint4 av1 = make_uint4(lo1.x, lo1.y, 0u, 0u);
            f32x16 acc0 = __builtin_amdgcn_mfma_f32_32x32x16_f16(
                __builtin_bit_cast(f16x8, av0), bf, zacc, 0, 0, 0);
            f32x16 acc1 = __builtin_amdgcn_mfma_f32_32x32x16_f16(
                __builtin_bit_cast(f16x8, av1), bf, zacc, 0, 0, 0);
#pragma unroll
            for (int r = 0; r < 16; ++r)
                vmin[r] = fminf(fminf(vmin[r], acc0[r]), acc1[r]);  // v_min3
        }
    }

    // Reduce 16 regs -> 1, then across the two row-halves (lane ^ 32).
    float v = vmin[0];
#pragma unroll
    for (int r = 1; r < 16; ++r) v = fminf(v, vmin[r]);
    v = fminf(v, __shfl_xor(v, 32));
    float d = v + fmaf(x0, x0, fmaf(x1, x1, x2 * x2));  // + |x|^2 in f32

    // Sum d over the 32 cols of this wave (both halves hold identical values).
#pragma unroll
    for (int off = 16; off > 0; off >>= 1) d += __shfl_xor(d, off);
    if (lane == 0) swave[wave] = d;
    __syncthreads();
    if (tid == 0) {
        float s = swave[0] + swave[1] + swave[2] + swave[3];
        int bid = blockIdx.x + gridDim.x * (blockIdx.y + gridDim.y * blockIdx.z);
        partials[bid] = s;
    }
}

// partials[0 .. nPerDir-1] = dir0 block sums, [nPerDir .. 2*nPerDir-1] = dir1.
__global__ __launch_bounds__(512) void finalize(
    const float* __restrict__ partials, const float* __restrict__ fbpp,
    float* __restrict__ out, int nPerDir, int totalPts)
{
    __shared__ float sw[8];
    const int tid = threadIdx.x;
    float v = (tid < 2 * nPerDir) ? partials[tid] : 0.0f;
#pragma unroll
    for (int off = 32; off > 0; off >>= 1) v += __shfl_xor(v, off);
    if ((tid & 63) == 0) sw[tid >> 6] = v;
    __syncthreads();
    if (tid == 0) {
        float s0 = sw[0] + sw[1] + sw[2] + sw[3];  // dir0 (waves 0-3)
        float s1 = sw[4] + sw[5] + sw[6] + sw[7];  // dir1 (waves 4-7)
        float inv = 1.0f / (float)totalPts;
        float dist = s0 * inv + s1 * inv;
        float rate = fbpp[0];
        out[0] = dist + rate;
        out[1] = dist;
        out[2] = rate;
    }
}

extern "C" void kernel_launch(void* const* d_in, const int* in_sizes, int n_in,
                              void* d_out, int out_size, void* d_ws, size_t ws_size,
                              hipStream_t stream) {
    const float* pred = (const float*)d_in[0];
    const float* targ = (const float*)d_in[1];
    const float* fbpp = (const float*)d_in[2];
    float* out = (float*)d_out;

    const int B = 4;
    const int N = in_sizes[0] / (B * 3);   // 8192
    float* partials = (float*)d_ws;        // 2 * B * (N/XPB) floats

    dim3 grid(N / XPB, B, 2);              // (64, 4, 2) = 512 blocks
    chamfer_kernel<<<grid, THREADS, 0, stream>>>(pred, targ, partials, N);

    const int nPerDir = (N / XPB) * B;     // 256
    finalize<<<1, 512, 0, stream>>>(partials, fbpp, out, nPerDir, B * N);
}